// Round 5
// baseline (908.564 us; speedup 1.0000x reference)
//
#include <hip/hip_runtime.h>

// BinarizeLayer forward (r5 = r4 with legal nontemporal stores):
//   phase 1 : coalesced load of CONT halves only -> LDS (stride 17, 2-way = free)
//   phase 3a: disc passthrough as direct global->global copy (no LDS), issued
//             BEFORE the first barrier so stores stream during LDS staging
//   phase 2 : one row per thread -- byte-identical math to the verified r3 kernel
//   phase 3b: 96 fully-coalesced nontemporal float4 stores (one-hot regions)
//   loss    : wave shuffle-reduce -> per-block partial -> finalize kernel
// LDS 39.4 KB -> 23.2 KB => 4 -> 6 blocks/CU.
// NB: __builtin_nontemporal_store needs a clang vector type, not HIP float4.

typedef float vfloat4 __attribute__((ext_vector_type(4)));

constexpr int kB      = 524288;
constexpr int kF      = 16;
constexpr int kK1     = 16;
constexpr int kK2     = 8;
constexpr int kRowIn  = 32;    // DISC + F
constexpr int kRowOut = 400;   // DISC + F*K1 + F*K2
constexpr float kEps  = 0.001f;
constexpr int kTPB    = 256;   // threads per block == rows per block
constexpr int kGrid   = kB / kTPB;     // 2048 blocks
constexpr int kXStride = 17;   // LDS cont row stride in floats

template <int K>
__device__ __forceinline__ int soft_argmax_loss(const float* __restrict__ dd,
                                                double& lacc)
{
#pragma clang fp contract(off)
    // ---- loss term: sum_k d * softmax(-d). Fast exp: output is threshold-checked.
    float se = 0.f, sde = 0.f;
#pragma unroll
    for (int k = 0; k < K; ++k) {
        float e = __expf(-dd[k]);
        se += e; sde += dd[k] * e;
    }
    lacc += (double)(sde / se);

    // ---- argmax(softmax(-100*d)) fast path: first-occurrence argmax of z ----
    float z[K];
#pragma unroll
    for (int k = 0; k < K; ++k) z[k] = -100.0f * dd[k];
    float m = z[0]; int kmax = 0;
#pragma unroll
    for (int k = 1; k < K; ++k) {
        if (z[k] > m) { m = z[k]; kmax = k; }
    }

    // argmax can only move to an EARLIER j<kmax if p_j rounds equal to p_kmax,
    // which needs z_j within ~1 ulp of m. Conservative guard; exact expf+IEEE-div
    // replication only then (exec-masked, ~never taken). Bit-faithful to numpy.
    bool cand = false;
#pragma unroll
    for (int k = 0; k < K; ++k)
        cand |= (k < kmax) & (z[k] >= m - 2.4e-7f);
    if (cand) {
        float e2[K]; float ss = 0.f;
        for (int k = 0; k < K; ++k) { e2[k] = expf(z[k] - m); ss += e2[k]; }
        int km = 0; float pmax = e2[0] / ss;
        for (int k = 1; k < K; ++k) {
            float p = e2[k] / ss;
            if (p > pmax) { pmax = p; km = k; }
        }
        kmax = km;
    }
    return kmax;
}

__global__ __launch_bounds__(kTPB) void binlayer_main(
    const float* __restrict__ x,
    const float* __restrict__ interval,
    const float* __restrict__ interval2,
    const float* __restrict__ i_min,
    float* __restrict__ out,
    double* __restrict__ partial)
{
#pragma clang fp contract(off)
    __shared__ float sC1[kF][kK1];
    __shared__ float sC2[kF][kK2];
    __shared__ float sCont[kTPB * kXStride];     // 17.4 KB
    __shared__ unsigned char sIdx[kTPB * kF];    // 4 KB
    __shared__ double sL[kTPB / 64];

    const int tid = threadIdx.x;

    // centers: i_min + fp32 cumsum of max(interval, eps), in k order
    if (tid < kF) {
        const float base = i_min[tid];
        float run = 0.f;
        for (int k = 0; k < kK1; ++k) {
            run += fmaxf(interval[tid * kK1 + k], kEps);
            sC1[tid][k] = base + run;
        }
        run = 0.f;
        for (int k = 0; k < kK2; ++k) {
            run += fmaxf(interval2[tid * kK2 + k], kEps);
            sC2[tid][k] = base + run;
        }
    }

    const long long rowBase = (long long)blockIdx.x * kTPB;
    const vfloat4* __restrict__ xin4 = (const vfloat4*)(x + rowBase * kRowIn);
    vfloat4* __restrict__ o4 = (vfloat4*)(out + rowBase * kRowOut);

    // ---------- phase 1: cont halves -> LDS (chunks 4..7 of each row) ----------
#pragma unroll
    for (int i = 0; i < 4; ++i) {
        int flat = i * kTPB + tid;           // 0..1023
        int r = flat >> 2, c = flat & 3;
        vfloat4 v = xin4[r * 8 + 4 + c];
        float* p = &sCont[r * kXStride + c * 4];
        p[0] = v.x; p[1] = v.y; p[2] = v.z; p[3] = v.w;
    }

    // ---------- phase 3a: disc passthrough, global->global (no LDS dep) ----------
#pragma unroll
    for (int i = 0; i < 4; ++i) {
        int flat = i * kTPB + tid;           // 0..1023
        int r = flat >> 2, c = flat & 3;
        vfloat4 v = xin4[r * 8 + c];         // L2-hit: lines fetched with phase 1
        __builtin_nontemporal_store(v, &o4[r * 100 + c]);
    }

    __syncthreads();

    // ---------- phase 2: one row per thread (math identical to r3) ----------
    double lacc = 0.0;
    const float* __restrict__ myc = &sCont[tid * kXStride];

#pragma unroll 1
    for (int f = 0; f < kF; ++f) {
        const float c = myc[f];

        float dd1[kK1];
#pragma unroll
        for (int k = 0; k < kK1; ++k) { float t = c - sC1[f][k]; dd1[k] = t * t; }
        int k1 = soft_argmax_loss<kK1>(dd1, lacc);

        float dd2[kK2];
#pragma unroll
        for (int k = 0; k < kK2; ++k) { float t = c - sC2[f][k]; dd2[k] = t * t; }
        int k2 = soft_argmax_loss<kK2>(dd2, lacc);

        sIdx[tid * kF + f] = (unsigned char)(k1 | (k2 << 4));
    }

    // loss: wave shuffle-reduce -> LDS -> one plain store per block
#pragma unroll
    for (int off = 32; off > 0; off >>= 1) lacc += __shfl_down(lacc, off);
    if ((tid & 63) == 0) sL[tid >> 6] = lacc;

    __syncthreads();   // sIdx visibility for phase 3b + sL for tid 0

    if (tid == 0) partial[blockIdx.x] = sL[0] + sL[1] + sL[2] + sL[3];

    // ---------- phase 3b: one-hot regions, coalesced nontemporal stores ----------
#pragma unroll 4
    for (int i = 0; i < 96; ++i) {
        unsigned idx = (unsigned)(i * kTPB + tid);   // 0..24575
        unsigned r = idx / 96u;                      // row in tile
        unsigned c = idx - r * 96u;                  // 0..95 -> row chunk 4+c
        vfloat4 o;
        if (c < 64u) {
            unsigned f = c >> 2, q = (c & 3u) * 4u;
            unsigned k = sIdx[r * kF + f] & 15u;
            o.x = (k == q + 0u) ? 1.f : 0.f;
            o.y = (k == q + 1u) ? 1.f : 0.f;
            o.z = (k == q + 2u) ? 1.f : 0.f;
            o.w = (k == q + 3u) ? 1.f : 0.f;
        } else {
            unsigned u = c - 64u, f = u >> 1, q = (u & 1u) * 4u;
            unsigned k = (unsigned)(sIdx[r * kF + f]) >> 4;
            o.x = (k == q + 0u) ? 1.f : 0.f;
            o.y = (k == q + 1u) ? 1.f : 0.f;
            o.z = (k == q + 2u) ? 1.f : 0.f;
            o.w = (k == q + 3u) ? 1.f : 0.f;
        }
        __builtin_nontemporal_store(o, &o4[r * 100u + 4u + c]);
    }
}

__global__ __launch_bounds__(256) void binlayer_finalize(
    const double* __restrict__ partial,
    float* __restrict__ out)
{
    __shared__ double sL[4];
    const int tid = threadIdx.x;
    double s = 0.0;
#pragma unroll
    for (int i = 0; i < kGrid / 256; ++i)       // 8 values each
        s += partial[i * 256 + tid];
#pragma unroll
    for (int off = 32; off > 0; off >>= 1) s += __shfl_down(s, off);
    if ((tid & 63) == 0) sL[tid >> 6] = s;
    __syncthreads();
    if (tid == 0)
        out[(long long)kB * kRowOut] =
            (float)((sL[0] + sL[1] + sL[2] + sL[3]) * (1.0 / (double)kB));
}

extern "C" void kernel_launch(void* const* d_in, const int* in_sizes, int n_in,
                              void* d_out, int out_size, void* d_ws, size_t ws_size,
                              hipStream_t stream)
{
    const float* x    = (const float*)d_in[0];
    const float* itv1 = (const float*)d_in[1];
    const float* itv2 = (const float*)d_in[2];
    const float* imin = (const float*)d_in[3];
    float* out = (float*)d_out;
    double* partial = (double*)d_ws;   // kGrid doubles = 16 KB

    binlayer_main<<<kGrid, kTPB, 0, stream>>>(x, itv1, itv2, imin, out, partial);
    binlayer_finalize<<<1, 256, 0, stream>>>(partial, out);
}